// Round 1
// 306.131 us; speedup vs baseline: 2.5680x; 2.5680x over previous
//
#include <hip/hip_runtime.h>
#include <math.h>

#define HH 4
#define KK 8192
#define DD 1024
#define HD 256      // d per head
#define BB 8192
#define MARGINF 1.0625f

typedef __attribute__((ext_vector_type(8))) short short8;
typedef __attribute__((ext_vector_type(4))) float floatx4;

__device__ __forceinline__ unsigned short f2bf(float f) {
    unsigned int u = __float_as_uint(f);
    u += 0x7FFFu + ((u >> 16) & 1u);     // RNE
    return (unsigned short)(u >> 16);
}

__device__ __forceinline__ void gl_lds16(const unsigned short* g, char* l) {
    __builtin_amdgcn_global_load_lds(
        (const __attribute__((address_space(1))) unsigned int*)g,
        (__attribute__((address_space(3))) unsigned int*)l, 16, 0, 0);
}

__device__ __forceinline__ void gl_lds4(const float* g, char* l) {
    __builtin_amdgcn_global_load_lds(
        (const __attribute__((address_space(1))) unsigned int*)g,
        (__attribute__((address_space(3))) unsigned int*)l, 4, 0, 0);
}

// ---------------- e2 precompute: e2w exact, e2p = e2 + 1024 (positive-shift for int-key compare) ----------------
__global__ __launch_bounds__(256)
void vq_e2(const float* __restrict__ C, float* __restrict__ e2w, float* __restrict__ e2p) {
    int gid  = blockIdx.x * 256 + threadIdx.x;
    int code = gid >> 2;
    int part = gid & 3;
    const float4* p = (const float4*)&C[(size_t)code * HD + part * 64];
    float s = 0.f;
#pragma unroll
    for (int i = 0; i < 16; ++i) {
        float4 v = p[i];
        s = fmaf(v.x, v.x, s); s = fmaf(v.y, v.y, s);
        s = fmaf(v.z, v.z, s); s = fmaf(v.w, v.w, s);
    }
    s += __shfl_xor(s, 1);
    s += __shfl_xor(s, 2);
    if (part == 0) { e2w[code] = s; e2p[code] = s + 1024.0f; }
}

// ---------------- convert codebook to bf16 ----------------
__global__ __launch_bounds__(256)
void vq_cvtC(const float* __restrict__ C, unsigned short* __restrict__ Cbf) {
    size_t i = ((size_t)blockIdx.x * 256 + threadIdx.x) * 8;
    float4 a = *(const float4*)&C[i];
    float4 b = *(const float4*)&C[i + 4];
    short8 o;
    o[0] = (short)f2bf(a.x); o[1] = (short)f2bf(a.y); o[2] = (short)f2bf(a.z); o[3] = (short)f2bf(a.w);
    o[4] = (short)f2bf(b.x); o[5] = (short)f2bf(b.y); o[6] = (short)f2bf(b.z); o[7] = (short)f2bf(b.w);
    *(short8*)&Cbf[i] = o;
}

// ======== pipelined main kernel helpers: raw barrier + counted vmcnt (never drain to 0 in loop) ========
#define WAITV(N) asm volatile("s_waitcnt vmcnt(" #N ")" ::: "memory")
#define VQ_SYNC() do { __builtin_amdgcn_s_barrier(); __builtin_amdgcn_sched_barrier(0); } while (0)

// stage B sub-tile for step SB into ring buffer SB&3 (4 x global_load_lds dwordx4 per thread)
#define VQ_STAGE(SB)                                                                                   \
    do {                                                                                               \
        const int ch1_ = (SB) >> 2, ks1_ = (SB) & 3;                                                   \
        _Pragma("unroll")                                                                              \
        for (int j = 0; j < 4; ++j) {                                                                  \
            const unsigned short* gp_ = CbfH + (size_t)(ch1_ * 128 + j * 32 + c0) * HD + ks1_ * 64 + ksegS * 8; \
            gl_lds16(gp_, smB + (((SB) & 3) << 14) + ((j * 256 + wid * 64) << 4));                     \
        }                                                                                              \
    } while (0)

// stage e2p for chunk CH2 into e2ring slot CH2&3 (1 x global_load_lds dword per thread; waves 2,3 duplicate 0,1)
#define VQ_STAGE_E2(CH2)                                                                               \
    do {                                                                                               \
        const int chc_ = (CH2) > 63 ? 63 : (CH2);                                                      \
        const float* gp_ = e2p + (size_t)h * KK + chc_ * 128 + ((wid & 1) << 6) + lane;                \
        gl_lds4(gp_, (char*)&e2ring[(((CH2) & 3) << 7) + ((wid & 1) << 6)]);                           \
    } while (0)

#define VQ_COMPUTE(KST, CH, S)                                                                         \
    do {                                                                                               \
        if ((KST) == 0) {                                                                              \
            e0 = e2ring[(((CH) & 3) << 7) + wid * 32 + cl];                                            \
            e1 = e2ring[(((CH) & 3) << 7) + wid * 32 + 16 + cl];                                       \
            floatx4 zz = {0.f, 0.f, 0.f, 0.f};                                                         \
            _Pragma("unroll")                                                                          \
            for (int tm = 0; tm < 4; ++tm) { acc[tm][0] = zz; acc[tm][1] = zz; }                       \
        }                                                                                              \
        const char* bb_ = smB + (((S) & 3) << 14);                                                     \
        __builtin_amdgcn_s_setprio(1);                                                                 \
        _Pragma("unroll")                                                                              \
        for (int kc = 0; kc < 2; ++kc) {                                                               \
            short8 b0 = *(const short8*)(bb_ + roff[0][kc]);                                           \
            short8 b1 = *(const short8*)(bb_ + roff[1][kc]);                                           \
            const int ai = (KST) * 2 + kc;                                                             \
            _Pragma("unroll")                                                                          \
            for (int tm = 0; tm < 4; ++tm) {                                                           \
                acc[tm][0] = __builtin_amdgcn_mfma_f32_16x16x32_bf16(afrag[tm][ai], b0, acc[tm][0], 0, 0, 0); \
                acc[tm][1] = __builtin_amdgcn_mfma_f32_16x16x32_bf16(afrag[tm][ai], b1, acc[tm][1], 0, 0, 0); \
            }                                                                                          \
        }                                                                                              \
        __builtin_amdgcn_s_setprio(0);                                                                 \
        if ((KST) == 3) {                                                                              \
            const int ctag = (CH) << 1;                                                                \
            _Pragma("unroll")                                                                          \
            for (int tn = 0; tn < 2; ++tn) {                                                           \
                const float ee = tn ? e1 : e0;                                                         \
                const int tag = ctag | tn;                                                             \
                _Pragma("unroll")                                                                      \
                for (int tm = 0; tm < 4; ++tm)                                                         \
                    _Pragma("unroll")                                                                  \
                    for (int r = 0; r < 4; ++r) {                                                      \
                        float dp = fmaf(-2.0f, acc[tm][tn][r], ee);                                    \
                        int key = (__float_as_int(dp) & 0xFFFFFF80) | tag;                             \
                        const int sl = tm * 4 + r;                                                     \
                        int mx = max(key, best1[sl]);                                                  \
                        best1[sl] = min(best1[sl], key);                                               \
                        best2[sl] = min(best2[sl], mx);                                                \
                    }                                                                                  \
            }                                                                                          \
        }                                                                                              \
    } while (0)

// ---------------- main: MFMA scores (64 rows x 8192 codes per block) + margin rescore + epilogue ----------------
__global__ __launch_bounds__(256, 2)
void vq_score(const float* __restrict__ X, const float* __restrict__ C,
              const unsigned short* __restrict__ Cbf,
              const float* __restrict__ e2w, const float* __restrict__ e2p,
              float* __restrict__ elw,
              float* __restrict__ out_q, float* __restrict__ out_codes) {
    __shared__ __align__(16) char smB[65536];   // B ring: 4 x (128 codes x 64 k bf16)
    __shared__ float e2ring[512];               // e2p ring: 4 chunks x 128 codes
    __shared__ int   rowWave[256];
    __shared__ int   rowMinS[64];
    __shared__ int   cntA[64];
    __shared__ int   listI[64 * 8];
    __shared__ float pairD[128];
    __shared__ int   pairI[128];
    __shared__ int   codeS[64];

    const int tid = threadIdx.x;
    const int bi  = blockIdx.x;
    const int x   = bi & 7;                // ~XCD id under round-robin dispatch
    const int h   = x & 3;                 // one head per XCD -> codebook L2-resident
    const int rowbase = (((bi >> 3) << 1) + (x >> 2)) * 64;
    const int wid  = tid >> 6;
    const int lane = tid & 63;
    const int cl = lane & 15;
    const int qh = lane >> 4;

    // ---- A fragments in registers: rows rowbase+tm*16+cl, k = i*32 + qh*8 + j ----
    short8 afrag[4][8];
#pragma unroll
    for (int tm = 0; tm < 4; ++tm) {
        const float* rp = X + (size_t)(rowbase + tm * 16 + cl) * DD + h * HD + qh * 8;
#pragma unroll
        for (int i = 0; i < 8; ++i) {
            float4 v0 = *(const float4*)(rp + i * 32);
            float4 v1 = *(const float4*)(rp + i * 32 + 4);
            short8 t;
            t[0] = (short)f2bf(v0.x); t[1] = (short)f2bf(v0.y); t[2] = (short)f2bf(v0.z); t[3] = (short)f2bf(v0.w);
            t[4] = (short)f2bf(v1.x); t[5] = (short)f2bf(v1.y); t[6] = (short)f2bf(v1.z); t[7] = (short)f2bf(v1.w);
            afrag[tm][i] = t;
        }
    }

    int best1[16], best2[16];
#pragma unroll
    for (int i = 0; i < 16; ++i) { best1[i] = 0x7FFFFFFF; best2[i] = 0x7FFFFFFF; }

    const unsigned short* CbfH = Cbf + (size_t)h * KK * HD;
    // staging constants: slot lin = j*256+tid holds (code=lin>>3, kperm=lin&7), kseg = kperm ^ (code&7)
    const int c0    = tid >> 3;                    // 0..31
    const int ksegS = (tid & 7) ^ (c0 & 7);
    // frag read byte-offsets (tn, kc): code_local*128 + ((kc*4+qh)^(cl&7))*16
    int roff[2][2];
#pragma unroll
    for (int tn = 0; tn < 2; ++tn)
#pragma unroll
        for (int kc = 0; kc < 2; ++kc)
            roff[tn][kc] = (wid * 32 + tn * 16 + cl) * 128 + ((((kc << 2) + qh) ^ (cl & 7)) << 4);

    floatx4 acc[4][2];
    float e0 = 0.f, e1 = 0.f;

    // ---- prologue: e2 chunks 0,1 then B steps 0..2 (3-deep prefetch). 14 loads in flight. ----
    VQ_STAGE_E2(0);
    VQ_STAGE_E2(1);
    VQ_STAGE(0);
    VQ_STAGE(1);
    VQ_STAGE(2);

    // ---- steady loop: per substep {wait counted vmcnt; raw barrier; issue stage(s+3); 16 MFMA} ----
    // vmcnt ledger (verified): stage(s) landed iff outstanding <= loads-issued-after-stage(s):
    //   substep0: 8 (stages s+1,s+2)         substep1..3: 9 (8 + the e2 load of substep0)
    for (int ch = 0; ch < 63; ++ch) {
        const int s0 = ch << 2;
        WAITV(8); VQ_SYNC(); VQ_STAGE(s0 + 3); VQ_STAGE_E2(ch + 2); VQ_COMPUTE(0, ch, s0 + 0);
        WAITV(9); VQ_SYNC(); VQ_STAGE(s0 + 4);                      VQ_COMPUTE(1, ch, s0 + 1);
        WAITV(9); VQ_SYNC(); VQ_STAGE(s0 + 5);                      VQ_COMPUTE(2, ch, s0 + 2);
        WAITV(9); VQ_SYNC(); VQ_STAGE(s0 + 6);                      VQ_COMPUTE(3, ch, s0 + 3);
    }
    // ---- epilogue chunk 63: no e2 issue; drain ledger 8,8,4,0 ----
    WAITV(8); VQ_SYNC(); VQ_STAGE(255); VQ_COMPUTE(0, 63, 252);
    WAITV(8); VQ_SYNC();                VQ_COMPUTE(1, 63, 253);
    WAITV(4); VQ_SYNC();                VQ_COMPUTE(2, 63, 254);
    WAITV(0); VQ_SYNC();                VQ_COMPUTE(3, 63, 255);

    // ---- per-row approx min: shuffle-min over the 16 cl lanes, then across waves via LDS ----
#pragma unroll
    for (int sl = 0; sl < 16; ++sl) {
        int m = best1[sl];
        m = min(m, __shfl_xor(m, 1));
        m = min(m, __shfl_xor(m, 2));
        m = min(m, __shfl_xor(m, 4));
        m = min(m, __shfl_xor(m, 8));
        if (cl == 0) {
            int row = (sl >> 2) * 16 + qh * 4 + (sl & 3);
            rowWave[wid * 64 + row] = m;
        }
    }
    __syncthreads();
    if (tid < 64) {
        rowMinS[tid] = min(min(rowWave[tid], rowWave[64 + tid]),
                           min(rowWave[128 + tid], rowWave[192 + tid]));
        cntA[tid] = 0;
    }
    __syncthreads();
    // ---- collect candidates within margin (64 slots x top2 per row) ----
#pragma unroll
    for (int sl = 0; sl < 16; ++sl) {
        const int row = (sl >> 2) * 16 + qh * 4 + (sl & 3);
        const float lim = __int_as_float(rowMinS[row]) + MARGINF;
#pragma unroll
        for (int t = 0; t < 2; ++t) {
            int key = t ? best2[sl] : best1[sl];
            float d = __int_as_float(key & 0xFFFFFF80);   // sentinel 0x7FFFFFFF -> NaN -> excluded
            if (d <= lim) {
                int chunk = (key >> 1) & 63, tn = key & 1;
                int code = chunk * 128 + wid * 32 + tn * 16 + cl;
                int pos = atomicAdd(&cntA[row], 1);
                if (pos < 8) listI[row * 8 + pos] = code;
            }
        }
    }
    __syncthreads();
    // ---- exact fp32 rescore (2 threads/row), identical rounding chain to the R1/R2-passing kernels ----
    if (tid < 128) {
        int row = tid >> 1, par = tid & 1;
        int n = min(cntA[row], 8);
        float bD = 1e38f; int bI = 0x7FFFFFFF;
        if (n == 1) {
            if (par == 0) { bD = -1e38f; bI = listI[row * 8]; }
        } else {
            const float* Xr = X + (size_t)(rowbase + row) * DD + h * HD;
            float p0 = 0, p1 = 0, p2 = 0, p3 = 0;
            for (int d = 0;   d < 64;  ++d) p0 = fmaf(Xr[d], Xr[d], p0);
            for (int d = 64;  d < 128; ++d) p1 = fmaf(Xr[d], Xr[d], p1);
            for (int d = 128; d < 192; ++d) p2 = fmaf(Xr[d], Xr[d], p2);
            for (int d = 192; d < 256; ++d) p3 = fmaf(Xr[d], Xr[d], p3);
            float x2 = __fadd_rn(__fadd_rn(p0, p1), __fadd_rn(p2, p3));
            for (int j = par; j < n; j += 2) {
                int idx = listI[row * 8 + j];
                const float* Cr = C + ((size_t)h * KK + idx) * HD;
                float a = 0.f;
                for (int d = 0; d < 256; ++d) a = fmaf(Xr[d], Cr[d], a);
                float t1 = fmaf(-2.0f, a, x2);
                float dist = __fadd_rn(t1, e2w[h * KK + idx]);
                if (dist < bD || (dist == bD && idx < bI)) { bD = dist; bI = idx; }
            }
        }
        pairD[tid] = bD; pairI[tid] = bI;
    }
    __syncthreads();
    if (tid < 64) {
        float d0 = pairD[tid * 2], d1 = pairD[tid * 2 + 1];
        int   i0 = pairI[tid * 2], i1 = pairI[tid * 2 + 1];
        int w = (d1 < d0 || (d1 == d0 && i1 < i0)) ? i1 : i0;
        codeS[tid] = w;
        out_codes[(size_t)(rowbase + tid) * HH + h] = (float)w;
    }
    __syncthreads();

    // ---- epilogue: quantized (STE value) + e_latent, exact as R1/R2 ----
    {
        int row = tid >> 2, part = tid & 3;
        int b = rowbase + row;
        int c = codeS[row];
        const float4* qp = (const float4*)&C[((size_t)h * KK + c) * HD + part * 64];
        const float4* xp = (const float4*)&X[(size_t)b * DD + h * HD + part * 64];
        float4*       op = (float4*)&out_q[(size_t)b * DD + h * HD + part * 64];
        float s = 0.f;
#pragma unroll
        for (int i = 0; i < 16; ++i) {
            float4 q4 = qp[i]; float4 x4 = xp[i]; float4 o;
            float d0 = __fsub_rn(q4.x, x4.x); o.x = __fadd_rn(x4.x, d0); s = fmaf(d0, d0, s);
            float d1 = __fsub_rn(q4.y, x4.y); o.y = __fadd_rn(x4.y, d1); s = fmaf(d1, d1, s);
            float d2 = __fsub_rn(q4.z, x4.z); o.z = __fadd_rn(x4.z, d2); s = fmaf(d2, d2, s);
            float d3 = __fsub_rn(q4.w, x4.w); o.w = __fadd_rn(x4.w, d3); s = fmaf(d3, d3, s);
            op[i] = o;
        }
        s += __shfl_xor(s, 1);
        s += __shfl_xor(s, 2);
        if (part == 0) elw[(size_t)b * HH + h] = s * (1.0f / 256.0f);
    }
}

// ---------------- loss: 0.25 * sum_h e_latent ----------------
__global__ __launch_bounds__(256)
void vq_loss(const float* __restrict__ elw, float* __restrict__ out_loss) {
    int b = blockIdx.x * 256 + threadIdx.x;
    if (b < BB) {
        float4 e = *(const float4*)&elw[(size_t)b * HH];
        out_loss[b] = 0.25f * (((e.x + e.y) + e.z) + e.w);
    }
}

// ================= fallback (proven R1 path, used if ws too small) =================
#define ROWS 64
#define KC   128
#define DC   32

__global__ __launch_bounds__(256, 3)
void vq_main(const float* __restrict__ X, const float* __restrict__ C,
             const float* __restrict__ e2w, float* __restrict__ elw,
             float* __restrict__ out_q, float* __restrict__ out_codes) {
    __shared__ float smem[2048 + 4096];
    float* Xs = smem;
    float* Cs = smem + 2048;
    __shared__ float x2s[ROWS];
    __shared__ int   codeSf[ROWS];

    const int tid     = threadIdx.x;
    const int h       = blockIdx.y;
    const int rowbase = blockIdx.x * ROWS;

    {
        int row = tid >> 2, part = tid & 3;
        const float4* xp = (const float4*)&X[(size_t)(rowbase + row) * DD + h * HD + part * 64];
        float s = 0.f;
#pragma unroll
        for (int i = 0; i < 16; ++i) {
            float4 v = xp[i];
            s = fmaf(v.x, v.x, s); s = fmaf(v.y, v.y, s);
            s = fmaf(v.z, v.z, s); s = fmaf(v.w, v.w, s);
        }
        s += __shfl_xor(s, 1);
        s += __shfl_xor(s, 2);
        if (part == 0) x2s[row] = s;
    }
    __syncthreads();

    const int rg = tid & 7;
    const int cg = tid >> 3;
    const int r0 = rg * 8;

    float x2r[8];
#pragma unroll
    for (int r = 0; r < 8; ++r) x2r[r] = x2s[r0 + r];

    float mn[8]; int mi[8];
#pragma unroll
    for (int r = 0; r < 8; ++r) { mn[r] = 3.402823466e38f; mi[r] = 0; }

    for (int kb = 0; kb < KK; kb += KC) {
        float acc[8][4];
#pragma unroll
        for (int r = 0; r < 8; ++r)
#pragma unroll
            for (int c = 0; c < 4; ++c) acc[r][c] = 0.f;

        for (int db = 0; db < HD; db += DC) {
            __syncthreads();
#pragma unroll
            for (int rep = 0; rep < 2; ++rep) {
                int i = tid + rep * 256;
                int row = i >> 3, q = i & 7;
                float4 v = *(const float4*)&X[(size_t)(rowbase + row) * DD + h * HD + db + q * 4];
                int col = row ^ ((q & 3) << 3);
                Xs[(q * 4 + 0) * 64 + col] = v.x;
                Xs[(q * 4 + 1) * 64 + col] = v.y;
                Xs[(q * 4 + 2) * 64 + col] = v.z;
                Xs[(q * 4 + 3) * 64 + col] = v.w;
            }
#pragma unroll
            for (int rep = 0; rep < 4; ++rep) {
                int i = tid + rep * 256;
                int code = i >> 3, q = i & 7;
                float4 v = *(const float4*)&C[((size_t)(h * KK + kb + code)) * HD + db + q * 4];
                int col = code ^ ((q & 3) << 3);
                Cs[(q * 4 + 0) * 128 + col] = v.x;
                Cs[(q * 4 + 1) * 128 + col] = v.y;
                Cs[(q * 4 + 2) * 128 + col] = v.z;
                Cs[(q * 4 + 3) * 128 + col] = v.w;
            }
            __syncthreads();
#pragma unroll
            for (int t = 0; t < DC; ++t) {
                int sw = ((t >> 2) & 3) << 3;
                const float4 xa = *(const float4*)&Xs[t * 64 + (r0 ^ sw)];
                const float4 xb = *(const float4*)&Xs[t * 64 + ((r0 ^ sw) + 4)];
                const float4 cv = *(const float4*)&Cs[t * 128 + ((cg * 4) ^ sw)];
                float xv[8] = {xa.x, xa.y, xa.z, xa.w, xb.x, xb.y, xb.z, xb.w};
                float clv[4] = {cv.x, cv.y, cv.z, cv.w};
#pragma unroll
                for (int r = 0; r < 8; ++r)
#pragma unroll
                    for (int c = 0; c < 4; ++c)
                        acc[r][c] = fmaf(xv[r], clv[c], acc[r][c]);
            }
        }
        const float4 e2v = *(const float4*)&e2w[h * KK + kb + cg * 4];
        float e2a[4] = {e2v.x, e2v.y, e2v.z, e2v.w};
#pragma unroll
        for (int c = 0; c < 4; ++c) {
            int kidx = kb + cg * 4 + c;
#pragma unroll
            for (int r = 0; r < 8; ++r) {
                float t1   = x2r[r] - 2.0f * acc[r][c];
                float dist = __fadd_rn(t1, e2a[c]);
                if (dist < mn[r]) { mn[r] = dist; mi[r] = kidx; }
            }
        }
    }

    __syncthreads();
    float* redm = smem;
    int*   redi = (int*)(smem + 2048);
#pragma unroll
    for (int r = 0; r < 8; ++r) {
        redm[cg * 64 + r0 + r] = mn[r];
        redi[cg * 64 + r0 + r] = mi[r];
    }
    __syncthreads();
    if (tid < ROWS) {
        int row = tid;
        float best = redm[row]; int bi2 = redi[row];
        for (int gg = 1; gg < 32; ++gg) {
            float m = redm[gg * 64 + row]; int ii = redi[gg * 64 + row];
            if (m < best || (m == best && ii < bi2)) { best = m; bi2 = ii; }
        }
        codeSf[row] = bi2;
        out_codes[(size_t)(rowbase + row) * HH + h] = (float)bi2;
    }
    __syncthreads();

    {
        int row = tid >> 2, part = tid & 3;
        int b = rowbase + row;
        int c = codeSf[row];
        const float4* qp = (const float4*)&C[((size_t)(h * KK + c)) * HD + part * 64];
        const float4* xp = (const float4*)&X[(size_t)b * DD + h * HD + part * 64];
        float4*       op = (float4*)&out_q[(size_t)b * DD + h * HD + part * 64];
        float s = 0.f;
#pragma unroll
        for (int i = 0; i < 16; ++i) {
            float4 q4 = qp[i]; float4 x4 = xp[i]; float4 o;
            float d0 = __fsub_rn(q4.x, x4.x); o.x = __fadd_rn(x4.x, d0); s = fmaf(d0, d0, s);
            float d1 = __fsub_rn(q4.y, x4.y); o.y = __fadd_rn(x4.y, d1); s = fmaf(d1, d1, s);
            float d2 = __fsub_rn(q4.z, x4.z); o.z = __fadd_rn(x4.z, d2); s = fmaf(d2, d2, s);
            float d3 = __fsub_rn(q4.w, x4.w); o.w = __fadd_rn(x4.w, d3); s = fmaf(d3, d3, s);
            op[i] = o;
        }
        s += __shfl_xor(s, 1);
        s += __shfl_xor(s, 2);
        if (part == 0) elw[(size_t)b * HH + h] = s * (1.0f / 256.0f);
    }
}

extern "C" void kernel_launch(void* const* d_in, const int* in_sizes, int n_in,
                              void* d_out, int out_size, void* d_ws, size_t ws_size,
                              hipStream_t stream) {
    const float* X = (const float*)d_in[0];   // (B,1,D) fp32
    const float* C = (const float*)d_in[1];   // (H,K,d) fp32
    float* out      = (float*)d_out;
    float* out_loss = out;                                 // [B]
    float* out_q    = out + BB;                            // [B*D]
    float* out_code = out + BB + (size_t)BB * DD;          // [B*H] as float
    float* e2w = (float*)d_ws;                             // [H*K]
    float* e2p = e2w + (size_t)HH * KK;                    // [H*K] shifted
    float* elw = e2p + (size_t)HH * KK;                    // [B*H]
    unsigned short* Cbf = (unsigned short*)(elw + (size_t)BB * HH);  // [H*K*d] bf16

    const size_t need = ((size_t)2 * HH * KK + (size_t)BB * HH) * 4 + (size_t)HH * KK * HD * 2;

    if (ws_size >= need) {
        vq_e2<<<512, 256, 0, stream>>>(C, e2w, e2p);
        vq_cvtC<<<(HH * KK * HD / 8) / 256, 256, 0, stream>>>(C, Cbf);
        vq_score<<<512, 256, 0, stream>>>(X, C, Cbf, e2w, e2p, elw, out_q, out_code);
        vq_loss<<<BB / 256, 256, 0, stream>>>(elw, out_loss);
    } else {
        vq_e2<<<512, 256, 0, stream>>>(C, e2w, e2p);
        dim3 grid(BB / ROWS, HH);
        vq_main<<<grid, 256, 0, stream>>>(X, C, e2w, elw, out_q, out_code);
        vq_loss<<<BB / 256, 256, 0, stream>>>(elw, out_loss);
    }
}